// Round 1
// baseline (183.463 us; speedup 1.0000x reference)
//
#include <hip/hip_runtime.h>

#define TW 32
#define TH 32
#define HALO 5
#define IW (TW + 2*HALO)   // 42
#define IH (TH + 2*HALO)   // 42
#define NTHREADS 256

__device__ __forceinline__ float wave_reduce(float v) {
    #pragma unroll
    for (int off = 32; off > 0; off >>= 1)
        v += __shfl_down(v, off, 64);
    return v;
}

__global__ __launch_bounds__(NTHREADS) void ssim_main_kernel(
    const float* __restrict__ fused,
    const float* __restrict__ img_a,
    const float* __restrict__ img_b,
    float* __restrict__ accum,
    int W, int H)
{
    __shared__ float sp[IH][IW];
    __shared__ float sa[IH][IW];
    __shared__ float sb[IH][IW];
    __shared__ float hp [IH][TW];
    __shared__ float ha [IH][TW];
    __shared__ float hb [IH][TW];
    __shared__ float hpp[IH][TW];
    __shared__ float haa[IH][TW];
    __shared__ float hbb[IH][TW];
    __shared__ float hpa[IH][TW];
    __shared__ float hpb[IH][TW];
    __shared__ float red[NTHREADS / 64];

    const int tid = threadIdx.x;
    const int n  = blockIdx.z;
    const int y0 = blockIdx.y * TH;
    const int x0 = blockIdx.x * TW;
    const size_t img_off = (size_t)n * W * H;
    const float* Fp = fused + img_off;
    const float* Ap = img_a + img_off;
    const float* Bp = img_b + img_off;

    // Gaussian weights (normalized 1-D; separable outer product == ref 2-D kernel)
    float g[11];
    {
        float s = 0.f;
        #pragma unroll
        for (int i = 0; i < 11; ++i) {
            float c = (float)(i - 5);
            g[i] = expf(-c * c / 4.5f);   // 2*sigma^2 = 4.5
            s += g[i];
        }
        float inv = 1.f / s;
        #pragma unroll
        for (int i = 0; i < 11; ++i) g[i] *= inv;
    }

    // ---- stage inputs (zero-padded halo), map [-1,1] -> [0,1] ----
    for (int idx = tid; idx < IH * IW; idx += NTHREADS) {
        int r = idx / IW, c = idx % IW;
        int gy = y0 + r - HALO, gx = x0 + c - HALO;
        float p = 0.f, a = 0.f, b = 0.f;
        if (gy >= 0 && gy < H && gx >= 0 && gx < W) {
            size_t o = (size_t)gy * W + gx;
            p = (Fp[o] + 1.f) * 0.5f;
            a = (Ap[o] + 1.f) * 0.5f;
            b = (Bp[o] + 1.f) * 0.5f;
        }
        sp[r][c] = p; sa[r][c] = a; sb[r][c] = b;
    }
    __syncthreads();

    // ---- horizontal 11-tap pass: 8 windowed sums ----
    for (int idx = tid; idx < IH * TW; idx += NTHREADS) {
        int r = idx / TW, c = idx % TW;
        float vp = 0, va = 0, vb = 0, vpp = 0, vaa = 0, vbb = 0, vpa = 0, vpb = 0;
        #pragma unroll
        for (int t = 0; t < 11; ++t) {
            float w = g[t];
            float p = sp[r][c + t];
            float a = sa[r][c + t];
            float b = sb[r][c + t];
            vp  += w * p;     va  += w * a;     vb  += w * b;
            vpp += w * p * p; vaa += w * a * a; vbb += w * b * b;
            vpa += w * p * a; vpb += w * p * b;
        }
        hp [r][c] = vp;  ha [r][c] = va;  hb [r][c] = vb;
        hpp[r][c] = vpp; haa[r][c] = vaa; hbb[r][c] = vbb;
        hpa[r][c] = vpa; hpb[r][c] = vpb;
    }
    __syncthreads();

    // ---- vertical 11-tap pass + SSIM map + accumulate ----
    const float C1v = 1e-4f;   // 0.01^2
    const float C2v = 9e-4f;   // 0.03^2
    float acc = 0.f;
    for (int idx = tid; idx < TH * TW; idx += NTHREADS) {
        int r = idx / TW, c = idx % TW;
        float mp = 0, ma = 0, mb = 0, mpp = 0, maa = 0, mbb = 0, mpa = 0, mpb = 0;
        #pragma unroll
        for (int j = 0; j < 11; ++j) {
            float w = g[j];
            mp  += w * hp [r + j][c];
            ma  += w * ha [r + j][c];
            mb  += w * hb [r + j][c];
            mpp += w * hpp[r + j][c];
            maa += w * haa[r + j][c];
            mbb += w * hbb[r + j][c];
            mpa += w * hpa[r + j][c];
            mpb += w * hpb[r + j][c];
        }
        float mp2 = mp * mp, ma2 = ma * ma, mb2 = mb * mb;
        float s_p  = mpp - mp2;
        float s_a  = maa - ma2;
        float s_b  = mbb - mb2;
        float s_pa = mpa - mp * ma;
        float s_pb = mpb - mp * mb;
        float na = (2.f * mp * ma + C1v) * (2.f * s_pa + C2v);
        float da = (mp2 + ma2 + C1v) * (s_p + s_a + C2v);
        float nb = (2.f * mp * mb + C1v) * (2.f * s_pb + C2v);
        float db = (mp2 + mb2 + C1v) * (s_p + s_b + C2v);
        acc += na / da + nb / db;
    }

    // ---- block reduction: wave shuffle -> LDS -> one atomic per block ----
    acc = wave_reduce(acc);
    if ((tid & 63) == 0) red[tid >> 6] = acc;
    __syncthreads();
    if (tid == 0) {
        float s = 0.f;
        #pragma unroll
        for (int i = 0; i < NTHREADS / 64; ++i) s += red[i];
        atomicAdd(accum, s);
    }
}

__global__ void ssim_finalize_kernel(const float* __restrict__ accum,
                                     float* __restrict__ out, float invTwoN) {
    out[0] = 1.f - accum[0] * invTwoN;
}

extern "C" void kernel_launch(void* const* d_in, const int* in_sizes, int n_in,
                              void* d_out, int out_size, void* d_ws, size_t ws_size,
                              hipStream_t stream) {
    const float* fused = (const float*)d_in[0];
    const float* img_a = (const float*)d_in[1];
    const float* img_b = (const float*)d_in[2];
    float* out = (float*)d_out;
    float* acc = (float*)d_ws;

    const int W = 512, H = 512, NIMG = 16;
    hipMemsetAsync(acc, 0, sizeof(float), stream);

    dim3 grid(W / TW, H / TH, NIMG);
    ssim_main_kernel<<<grid, NTHREADS, 0, stream>>>(fused, img_a, img_b, acc, W, H);

    const float invTwoN = 1.f / (2.f * (float)NIMG * (float)W * (float)H);
    ssim_finalize_kernel<<<1, 1, 0, stream>>>(acc, out, invTwoN);
}

// Round 2
// 151.244 us; speedup vs baseline: 1.2130x; 1.2130x over previous
//
#include <hip/hip_runtime.h>

#define NT 256
#define TW 32
#define TH 32
#define IH 42          // TH + 2*5 horizontal-pass rows
#define HP 33          // padded LDS row stride in float4 units
#define IMW 512
#define IMH 512

__device__ __forceinline__ float wave_reduce(float v) {
    #pragma unroll
    for (int off = 32; off > 0; off >>= 1)
        v += __shfl_down(v, off, 64);
    return v;
}

// Gaussian 1-D weights for ws=11, sigma=1.5 (separable outer product == ref 2-D kernel)
#define G0 0.00102838f
#define G1 0.00759840f
#define G2 0.03600077f
#define G3 0.10936070f
#define G4 0.21300590f
#define G5 0.26601190f

__global__ __launch_bounds__(NT, 3) void ssim_main_kernel(
    const float* __restrict__ fused,
    const float* __restrict__ img_a,
    const float* __restrict__ img_b,
    float* __restrict__ accum)
{
    // h-pass results, AoS float4: h4a = (p, a, b, pp), h4b = (aa, bb, pa, pb)
    __shared__ float4 h4a[IH * HP];
    __shared__ float4 h4b[IH * HP];
    __shared__ float red[NT / 64];

    const float g[11] = {G0, G1, G2, G3, G4, G5, G4, G3, G2, G1, G0};

    const int tid = threadIdx.x;
    const int x0 = blockIdx.x * TW;
    const int y0 = blockIdx.y * TH;
    const size_t ioff = (size_t)blockIdx.z * IMW * IMH;
    const float* Fp = fused + ioff;
    const float* Ap = img_a + ioff;
    const float* Bp = img_b + ioff;

    // ---------------- horizontal pass: global (L1/L2) -> registers -> LDS ----
    // task = (row r in [0,42), col-group cg in [0,8)); 4 output cols per task.
    // Window for output col 4cg+k (k=0..3) covers global cols x0+4cg+k-5 .. +5.
    // Load 5 aligned float4 chunks starting at xbase = x0+4cg-8 (i = 0..19;
    // used i in [3,17)). Products computed ONCE per loaded element.
    for (int idx = tid; idx < IH * (TW / 4); idx += NT) {
        const int r  = idx >> 3;
        const int cg = idx & 7;
        const int gy = y0 + r - 5;
        const bool yok = (gy >= 0) && (gy < IMH);

        float accs[4][8];
        #pragma unroll
        for (int k = 0; k < 4; ++k)
            #pragma unroll
            for (int q = 0; q < 8; ++q) accs[k][q] = 0.f;

        const int xbase = x0 + 4 * cg - 8;
        #pragma unroll
        for (int w = 0; w < 5; ++w) {
            const int xc = xbase + 4 * w;
            float4 p4 = {0.f, 0.f, 0.f, 0.f};
            float4 a4 = {0.f, 0.f, 0.f, 0.f};
            float4 b4 = {0.f, 0.f, 0.f, 0.f};
            if (yok && xc >= 0 && xc < IMW) {
                const size_t o = ((size_t)gy * IMW + xc) >> 2;  // float4 index
                p4 = ((const float4*)Fp)[o];
                a4 = ((const float4*)Ap)[o];
                b4 = ((const float4*)Bp)[o];
                // map [-1,1] -> [0,1] (OOB stays 0, matching zero padding of
                // the transformed image in the reference)
                p4.x = (p4.x + 1.f) * 0.5f; p4.y = (p4.y + 1.f) * 0.5f;
                p4.z = (p4.z + 1.f) * 0.5f; p4.w = (p4.w + 1.f) * 0.5f;
                a4.x = (a4.x + 1.f) * 0.5f; a4.y = (a4.y + 1.f) * 0.5f;
                a4.z = (a4.z + 1.f) * 0.5f; a4.w = (a4.w + 1.f) * 0.5f;
                b4.x = (b4.x + 1.f) * 0.5f; b4.y = (b4.y + 1.f) * 0.5f;
                b4.z = (b4.z + 1.f) * 0.5f; b4.w = (b4.w + 1.f) * 0.5f;
            }
            const float pe[4] = {p4.x, p4.y, p4.z, p4.w};
            const float ae[4] = {a4.x, a4.y, a4.z, a4.w};
            const float be[4] = {b4.x, b4.y, b4.z, b4.w};
            #pragma unroll
            for (int e = 0; e < 4; ++e) {
                const int i = 4 * w + e;
                if (i < 3 || i >= 17) continue;
                const int t = i - 3;                 // window position 0..13
                const float p = pe[e], a = ae[e], b = be[e];
                const float pp = p * p, aa = a * a, bb = b * b;
                const float pa = p * a, pb = p * b;
                #pragma unroll
                for (int k = 0; k < 4; ++k) {
                    const int j = t - k;             // tap index
                    if (j < 0 || j > 10) continue;
                    const float wt = g[j];
                    accs[k][0] += wt * p;  accs[k][1] += wt * a;
                    accs[k][2] += wt * b;  accs[k][3] += wt * pp;
                    accs[k][4] += wt * aa; accs[k][5] += wt * bb;
                    accs[k][6] += wt * pa; accs[k][7] += wt * pb;
                }
            }
        }
        #pragma unroll
        for (int k = 0; k < 4; ++k) {
            h4a[r * HP + 4 * cg + k] =
                make_float4(accs[k][0], accs[k][1], accs[k][2], accs[k][3]);
            h4b[r * HP + 4 * cg + k] =
                make_float4(accs[k][4], accs[k][5], accs[k][6], accs[k][7]);
        }
    }
    __syncthreads();

    // ---------------- vertical pass + SSIM, 4 consecutive rows per thread ----
    // thread = (col c in [0,32), row-group rg in [0,8)); ds_read_b128 pattern:
    // 32 consecutive lanes read 32 consecutive float4 -> conflict-free.
    const float C1v = 1e-4f;
    const float C2v = 9e-4f;
    float lsum = 0.f;
    {
        const int c  = tid & 31;
        const int rg = tid >> 5;
        const int R0 = rg * 4;

        float m[4][8];
        #pragma unroll
        for (int k = 0; k < 4; ++k)
            #pragma unroll
            for (int q = 0; q < 8; ++q) m[k][q] = 0.f;

        #pragma unroll
        for (int j = 0; j < 14; ++j) {
            const float4 va = h4a[(R0 + j) * HP + c];
            const float4 vb = h4b[(R0 + j) * HP + c];
            #pragma unroll
            for (int k = 0; k < 4; ++k) {
                const int t = j - k;                 // tap index
                if (t < 0 || t > 10) continue;
                const float wt = g[t];
                m[k][0] += wt * va.x; m[k][1] += wt * va.y;
                m[k][2] += wt * va.z; m[k][3] += wt * va.w;
                m[k][4] += wt * vb.x; m[k][5] += wt * vb.y;
                m[k][6] += wt * vb.z; m[k][7] += wt * vb.w;
            }
        }
        #pragma unroll
        for (int k = 0; k < 4; ++k) {
            const float mp = m[k][0], ma = m[k][1], mb = m[k][2];
            const float mpp = m[k][3], maa = m[k][4], mbb = m[k][5];
            const float mpa = m[k][6], mpb = m[k][7];
            const float mp2 = mp * mp, ma2 = ma * ma, mb2 = mb * mb;
            const float s_p  = mpp - mp2;
            const float s_a  = maa - ma2;
            const float s_b  = mbb - mb2;
            const float s_pa = mpa - mp * ma;
            const float s_pb = mpb - mp * mb;
            const float na = (2.f * mp * ma + C1v) * (2.f * s_pa + C2v);
            const float da = (mp2 + ma2 + C1v) * (s_p + s_a + C2v);
            const float nb = (2.f * mp * mb + C1v) * (2.f * s_pb + C2v);
            const float db = (mp2 + mb2 + C1v) * (s_p + s_b + C2v);
            lsum += na / da + nb / db;
        }
    }

    // ---------------- block reduction -> one atomic ----
    lsum = wave_reduce(lsum);
    if ((tid & 63) == 0) red[tid >> 6] = lsum;
    __syncthreads();
    if (tid == 0) {
        float s = 0.f;
        #pragma unroll
        for (int i = 0; i < NT / 64; ++i) s += red[i];
        atomicAdd(accum, s);
    }
}

__global__ void ssim_finalize_kernel(const float* __restrict__ accum,
                                     float* __restrict__ out, float invTwoN) {
    out[0] = 1.f - accum[0] * invTwoN;
}

extern "C" void kernel_launch(void* const* d_in, const int* in_sizes, int n_in,
                              void* d_out, int out_size, void* d_ws, size_t ws_size,
                              hipStream_t stream) {
    const float* fused = (const float*)d_in[0];
    const float* img_a = (const float*)d_in[1];
    const float* img_b = (const float*)d_in[2];
    float* out = (float*)d_out;
    float* acc = (float*)d_ws;

    const int NIMG = 16;
    hipMemsetAsync(acc, 0, sizeof(float), stream);

    dim3 grid(IMW / TW, IMH / TH, NIMG);
    ssim_main_kernel<<<grid, NT, 0, stream>>>(fused, img_a, img_b, acc);

    const float invTwoN = 1.f / (2.f * (float)NIMG * (float)IMW * (float)IMH);
    ssim_finalize_kernel<<<1, 1, 0, stream>>>(acc, out, invTwoN);
}